// Round 14
// baseline (216.713 us; speedup 1.0000x reference)
//
#include <hip/hip_runtime.h>

typedef unsigned short u16;
typedef unsigned int u32;
typedef __attribute__((ext_vector_type(8))) short bf16x8;
typedef __attribute__((ext_vector_type(4))) float f32x4;

#define AS1 __attribute__((address_space(1)))
#define AS3 __attribute__((address_space(3)))

__device__ __forceinline__ u16 f2bf(float f) {
  u32 u = __float_as_uint(f);
  u = (u + 0x7fffu + ((u >> 16) & 1u)) >> 16;
  return (u16)u;
}
__device__ __forceinline__ float bf2f(u16 v) { return __uint_as_float((u32)v << 16); }

__device__ __forceinline__ void gl16(const void* g, void* l) {
  __builtin_amdgcn_global_load_lds((AS1 void*)g, (AS3 void*)l, 16, 0, 0);
}

__device__ __forceinline__ float exp2a(float x) {
  float r;
  asm("v_exp_f32 %0, %1" : "=v"(r) : "v"(x));
  return r;
}
__device__ __forceinline__ u32 pk2(float lo, float hi) {
  u32 r;
  asm("v_cvt_pk_bf16_f32 %0, %1, %2" : "=v"(r) : "v"(lo), "v"(hi));
  return r;
}

#define LGKM0()                                         \
  do {                                                  \
    asm volatile("s_waitcnt lgkmcnt(0)" ::: "memory");  \
    __builtin_amdgcn_sched_barrier(0);                  \
  } while (0)
#define VMC0()                                          \
  do {                                                  \
    asm volatile("s_waitcnt vmcnt(0)" ::: "memory");    \
    __builtin_amdgcn_sched_barrier(0);                  \
  } while (0)

// ---- merged prep: weight transposes + LN1, one launch ----------------------
__global__ __launch_bounds__(256) void wprep_kernel(
    const float* __restrict__ Wq, const float* __restrict__ Wk,
    const float* __restrict__ Wv, const float* __restrict__ Wo,
    const float* __restrict__ W1, const float* __restrict__ W2,
    u16* __restrict__ WqkvT, u16* __restrict__ WoT,
    u16* __restrict__ W1T, u16* __restrict__ W2T,
    const float* __restrict__ x, const float* __restrict__ gamma,
    const float* __restrict__ beta, u16* __restrict__ xn_bf) {
  __shared__ float tile[32][33];
  __shared__ float rs[4], rq[4];
  int id = blockIdx.x;
  const int tx = threadIdx.x, ty = threadIdx.y;
  if (id >= 12288) {
    const int row = id - 12288;
    const int tid = ty * 32 + tx;
    const float* xr = x + (long)row * 1024;
    float4 v = *(const float4*)(xr + tid * 4);
    float s = v.x + v.y + v.z + v.w;
    float sq = v.x * v.x + v.y * v.y + v.z * v.z + v.w * v.w;
#pragma unroll
    for (int off = 1; off < 64; off <<= 1) {
      s += __shfl_xor(s, off);
      sq += __shfl_xor(sq, off);
    }
    const int w = tid >> 6, lane = tid & 63;
    if (lane == 0) { rs[w] = s; rq[w] = sq; }
    __syncthreads();
    s = rs[0] + rs[1] + rs[2] + rs[3];
    sq = rq[0] + rq[1] + rq[2] + rq[3];
    const float mean = s * (1.0f / 1024.0f);
    const float var = (sq - 1024.0f * mean * mean) * (1.0f / 1023.0f);
    const float rstd = rsqrtf(var + 1e-5f);
    float4 g4 = *(const float4*)(gamma + tid * 4);
    float4 b4 = *(const float4*)(beta + tid * 4);
    ushort4 ub;
    ub.x = f2bf((v.x - mean) * rstd * g4.x + b4.x);
    ub.y = f2bf((v.y - mean) * rstd * g4.y + b4.y);
    ub.z = f2bf((v.z - mean) * rstd * g4.z + b4.z);
    ub.w = f2bf((v.w - mean) * rstd * g4.w + b4.w);
    *(ushort4*)(xn_bf + (long)row * 1024 + tid * 4) = ub;
    return;
  }
  const float* ip;
  u16* op;
  int in_rs, R, c0, r0;
  if (id < 3072) {
    const int xq = id & 1, y = (id >> 1) & 31, z = id >> 6;
    const float* in = z < 16 ? Wq : (z < 32 ? Wk : Wv);
    ip = in + (long)(z & 15) * 65536;
    op = WqkvT + (long)z * 65536;
    in_rs = 64; R = 1024; c0 = xq * 32; r0 = y * 32;
  } else if (id < 4096) {
    id -= 3072;
    ip = Wo; op = WoT; in_rs = 1024; R = 1024;
    c0 = (id & 31) * 32; r0 = (id >> 5) * 32;
  } else if (id < 8192) {
    id -= 4096;
    ip = W1; op = W1T; in_rs = 4096; R = 1024;
    c0 = (id & 127) * 32; r0 = (id >> 7) * 32;
  } else {
    id -= 8192;
    ip = W2; op = W2T; in_rs = 1024; R = 4096;
    c0 = (id & 31) * 32; r0 = (id >> 5) * 32;
  }
#pragma unroll
  for (int i = 0; i < 4; ++i)
    tile[ty + i * 8][tx] = ip[(long)(r0 + ty + i * 8) * in_rs + c0 + tx];
  __syncthreads();
#pragma unroll
  for (int i = 0; i < 4; ++i)
    op[(long)(c0 + ty + i * 8) * R + r0 + tx] = f2bf(tile[tx][ty + i * 8]);
}

// ---- fused LN2: y = p0+p1+bo+xn_bf (bf16 residual), then layernorm ----------
__global__ __launch_bounds__(256) void ln2_fused_kernel(
    const u16* __restrict__ p0, const u16* __restrict__ p1,
    const float* __restrict__ bo, const u16* __restrict__ xnbf,
    const float* __restrict__ gamma, const float* __restrict__ beta,
    u16* __restrict__ obf) {
  const int row = blockIdx.x;
  const int tid = threadIdx.x;
  const long i4 = (long)row * 1024 + tid * 4;
  ushort4 a0 = *(const ushort4*)(p0 + i4);
  ushort4 a1 = *(const ushort4*)(p1 + i4);
  ushort4 xv = *(const ushort4*)(xnbf + i4);
  float4 bv = *(const float4*)(bo + tid * 4);
  float y0 = bf2f(a0.x) + bf2f(a1.x) + bv.x + bf2f(xv.x);
  float y1 = bf2f(a0.y) + bf2f(a1.y) + bv.y + bf2f(xv.y);
  float y2 = bf2f(a0.z) + bf2f(a1.z) + bv.z + bf2f(xv.z);
  float y3 = bf2f(a0.w) + bf2f(a1.w) + bv.w + bf2f(xv.w);
  float s = y0 + y1 + y2 + y3;
  float sq = y0 * y0 + y1 * y1 + y2 * y2 + y3 * y3;
#pragma unroll
  for (int off = 1; off < 64; off <<= 1) {
    s += __shfl_xor(s, off);
    sq += __shfl_xor(sq, off);
  }
  __shared__ float rs[4], rq[4];
  const int w = tid >> 6, lane = tid & 63;
  if (lane == 0) { rs[w] = s; rq[w] = sq; }
  __syncthreads();
  s = rs[0] + rs[1] + rs[2] + rs[3];
  sq = rq[0] + rq[1] + rq[2] + rq[3];
  const float mean = s * (1.0f / 1024.0f);
  const float var = (sq - 1024.0f * mean * mean) * (1.0f / 1023.0f);
  const float rstd = rsqrtf(var + 1e-5f);
  float4 g4 = *(const float4*)(gamma + tid * 4);
  float4 b4 = *(const float4*)(beta + tid * 4);
  ushort4 ub;
  ub.x = f2bf((y0 - mean) * rstd * g4.x + b4.x);
  ub.y = f2bf((y1 - mean) * rstd * g4.y + b4.y);
  ub.z = f2bf((y2 - mean) * rstd * g4.z + b4.z);
  ub.w = f2bf((y3 - mean) * rstd * g4.w + b4.w);
  *(ushort4*)(obf + i4) = ub;
}

// ---- FFN2 split-K=2 reduce: out = p0+p1 + b2 + yn_bf (bf16 residual) --------
__global__ __launch_bounds__(256) void ffn2_reduce_kernel(const u16* __restrict__ p,
                                                          const float* __restrict__ b2,
                                                          const u16* __restrict__ ynbf,
                                                          float* __restrict__ out) {
  const long i4 = ((long)blockIdx.x * 256 + threadIdx.x) * 4;
  ushort4 p0 = *(const ushort4*)(p + i4);
  ushort4 p1 = *(const ushort4*)(p + 4194304 + i4);
  ushort4 rr = *(const ushort4*)(ynbf + i4);
  const int nn = (int)(i4 & 1023);
  float4 bb = *(const float4*)(b2 + nn);
  float4 o;
  o.x = bf2f(p0.x) + bf2f(p1.x) + bb.x + bf2f(rr.x);
  o.y = bf2f(p0.y) + bf2f(p1.y) + bb.y + bf2f(rr.y);
  o.z = bf2f(p0.z) + bf2f(p1.z) + bb.z + bf2f(rr.z);
  o.w = bf2f(p0.w) + bf2f(p1.w) + bb.w + bf2f(rr.w);
  *(float4*)(out + i4) = o;
}

// ====== 128x128 bf16 GEMM (m97-class) =======================================
template <int EPI>
__global__ __launch_bounds__(256, 2) void gemm128_kernel(
    const u16* __restrict__ A, const u16* __restrict__ Bt,
    int K, int nk, int N,
    const float* bias0, const float* bias1, const float* bias2,
    void* out0, void* out1) {
  __shared__ __align__(16) u16 Asm[128 * 64];
  __shared__ __align__(16) u16 Bsm[128 * 64];
  const int tid = threadIdx.x;
  const int lane = tid & 63, w = tid >> 6;
  const int wm = w >> 1, wn = w & 1;
  const int q = lane & 15, g = lane >> 4;
  const long m0 = (long)blockIdx.x * 128;
  const long n0 = (long)blockIdx.y * 128;
  const int bz = blockIdx.z;
  const long koff = (long)bz * (long)nk * 64;

  f32x4 zero4 = {0.f, 0.f, 0.f, 0.f};
  f32x4 acc[4][4];
#pragma unroll
  for (int mi = 0; mi < 4; ++mi)
#pragma unroll
    for (int ni = 0; ni < 4; ++ni) acc[mi][ni] = zero4;

  for (int ks = 0; ks < nk; ++ks) {
    __syncthreads();
    const u16* ga = A + m0 * K + koff + ks * 64;
    const u16* gb = Bt + n0 * K + koff + ks * 64;
    const int base = w * 256;
#pragma unroll
    for (int i = 0; i < 4; ++i) {
      const int idx = base + i * 64 + lane;
      const int row = idx >> 3;
      const int lg = (idx & 7) ^ (row & 7);
      gl16(ga + (long)row * K + lg * 8, Asm + (long)(base + i * 64) * 8);
    }
#pragma unroll
    for (int i = 0; i < 4; ++i) {
      const int idx = base + i * 64 + lane;
      const int row = idx >> 3;
      const int lg = (idx & 7) ^ (row & 7);
      gl16(gb + (long)row * K + lg * 8, Bsm + (long)(base + i * 64) * 8);
    }
    __syncthreads();
#pragma unroll
    for (int half = 0; half < 2; ++half) {
      bf16x8 af[4], bfv[4];
#pragma unroll
      for (int mi = 0; mi < 4; ++mi) {
        const int row = wm * 64 + mi * 16 + q;
        const int ph = (half * 4 + g) ^ (row & 7);
        af[mi] = *(const bf16x8*)(Asm + row * 64 + ph * 8);
      }
#pragma unroll
      for (int ni = 0; ni < 4; ++ni) {
        const int row = wn * 64 + ni * 16 + q;
        const int ph = (half * 4 + g) ^ (row & 7);
        bfv[ni] = *(const bf16x8*)(Bsm + row * 64 + ph * 8);
      }
#pragma unroll
      for (int mi = 0; mi < 4; ++mi)
#pragma unroll
        for (int ni = 0; ni < 4; ++ni)
          acc[mi][ni] = __builtin_amdgcn_mfma_f32_16x16x32_bf16(af[mi], bfv[ni],
                                                                acc[mi][ni], 0, 0, 0);
    }
  }
#pragma unroll
  for (int mi = 0; mi < 4; ++mi) {
#pragma unroll
    for (int ni = 0; ni < 4; ++ni) {
      const long mbase = m0 + wm * 64 + mi * 16 + 4 * g;
      const long n = n0 + wn * 64 + ni * 16 + q;
      f32x4 a = acc[mi][ni];
      if constexpr (EPI == 0) {
        const int sel = (int)(n >> 10);
        const int nn = (int)(n & 1023);
        const float* bp = sel == 0 ? bias0 : (sel == 1 ? bias1 : bias2);
        const float bb2 = bp[nn];
        if (sel < 2) {
          const float sc = (sel == 0) ? 0.18033688011112043f : 1.0f;
          u16* qkp = (u16*)out0;
#pragma unroll
          for (int r = 0; r < 4; ++r)
            qkp[(mbase + r) * 2048 + n] = f2bf((a[r] + bb2) * sc);
        } else {
          const int bI = (int)(mbase >> 11);
          const int t = (int)(mbase & 2047);
          const int hh = nn >> 6, dh = nn & 63;
          ushort4 pk;
          pk.x = f2bf(a[0] + bb2); pk.y = f2bf(a[1] + bb2);
          pk.z = f2bf(a[2] + bb2); pk.w = f2bf(a[3] + bb2);
          *(ushort4*)((u16*)out1 + ((long)((bI * 16 + hh) * 64 + dh)) * 2048 + t) = pk;
        }
      } else if constexpr (EPI == 2) {
        u16* gp = (u16*)out0;
        const float bb2 = bias0[(int)n];
#pragma unroll
        for (int r = 0; r < 4; ++r) {
          const float xg = a[r] + bb2;
          const float ge = 0.5f * xg * (1.0f + erff(xg * 0.70710678118f));
          gp[(mbase + r) * N + n] = f2bf(ge);
        }
      } else {  // EPI == 5: bf16 partial per K-slice
        u16* pp = (u16*)out0 + (long)bz * 4096 * 1024;
#pragma unroll
        for (int r = 0; r < 4; ++r) pp[(mbase + r) * 1024 + n] = f2bf(a[r]);
      }
    }
  }
}

// ----- causal flash attention v5: R8 body + T15 QK(t+1) ∥ softmax/PV(t) -----
// K/V triple-buffered; S-tiles ping-pong in static regs (sA/sB).
__device__ __forceinline__ void attn_stage(const u16* kbase, const u16* vtb, int kb,
                                           u16* Kd, u16* Vd, int tid) {
#pragma unroll
  for (int it = 0; it < 2; ++it) {
    const int gi = it * 256 + tid;
    const int row = gi >> 3;
    const int lg = (gi & 7) ^ (row & 7);
    gl16(kbase + (long)(kb * 64 + row) * 2048 + lg * 8, Kd + gi * 8);
    gl16(vtb + (long)row * 2048 + kb * 64 + lg * 8, Vd + gi * 8);
  }
}

__device__ __forceinline__ void softmax_slab(const f32x4 st[4], bool diag, int qrow,
                                             int kb, int g, int q15,
                                             float& m2, float& l, u16* prow,
                                             float al[4]) {
  float sv[4][4];
  float rmax = -1e30f;
#pragma unroll
  for (int sub = 0; sub < 4; ++sub)
#pragma unroll
    for (int r = 0; r < 4; ++r) {
      float s_ = st[sub][r];
      if (diag) {
        const int key = kb * 64 + sub * 16 + 4 * g + r;
        s_ = (key > qrow) ? -1e30f : s_;
      }
      sv[sub][r] = s_;
      rmax = fmaxf(rmax, s_);
    }
  rmax = fmaxf(rmax, __shfl_xor(rmax, 16));
  rmax = fmaxf(rmax, __shfl_xor(rmax, 32));
  const float mnew = fmaxf(m2, rmax);
  const float alpha = exp2a(m2 - mnew);
  float psum = 0.f;
#pragma unroll
  for (int sub = 0; sub < 4; ++sub) {
    const float p0 = exp2a(sv[sub][0] - mnew);
    const float p1 = exp2a(sv[sub][1] - mnew);
    const float p2 = exp2a(sv[sub][2] - mnew);
    const float p3 = exp2a(sv[sub][3] - mnew);
    uint2 u;
    u.x = pk2(p0, p1);
    u.y = pk2(p2, p3);
    *(uint2*)(prow + sub * 16 + 4 * g) = u;
    psum += (p0 + p1) + (p2 + p3);
  }
  psum += __shfl_xor(psum, 16);
  psum += __shfl_xor(psum, 32);
  l = l * alpha + psum;
  m2 = mnew;
#pragma unroll
  for (int r = 0; r < 4; ++r) al[r] = __shfl(alpha, 4 * g + r);
}

#define MFMA_ __builtin_amdgcn_mfma_f32_16x16x32_bf16

// QK for both slabs from Kb -> D0/D1
#define QKCOMP(D0, D1, Kb)                                                     \
  do {                                                                         \
    _Pragma("unroll") for (int sub = 0; sub < 4; ++sub) {                      \
      const int row = sub * 16 + q15;                                          \
      const bf16x8 ka0 = *(const bf16x8*)((Kb) + row * 64 + ((g ^ (row & 7)) * 8)); \
      const bf16x8 ka1 = *(const bf16x8*)((Kb) + row * 64 + (((4 + g) ^ (row & 7)) * 8)); \
      f32x4 z0 = zero4, z1 = zero4;                                            \
      z0 = MFMA_(ka0, qa[0][0], z0, 0, 0, 0);                                  \
      z0 = MFMA_(ka1, qa[0][1], z0, 0, 0, 0);                                  \
      D0[sub] = z0;                                                            \
      z1 = MFMA_(ka0, qa[1][0], z1, 0, 0, 0);                                  \
      z1 = MFMA_(ka1, qa[1][1], z1, 0, 0, 0);                                  \
      D1[sub] = z1;                                                            \
    }                                                                          \
  } while (0)

// softmax + rescale + PV for tile KB using S regs S0/S1 and V buffer Vb
#define SMPV(S0, S1, KB, Vb)                                                   \
  do {                                                                         \
    float al0[4], al1[4];                                                      \
    softmax_slab(S0, (KB) >= 2 * qs, r0, (KB), g, q15, m20, l0,                \
                 &Psm[w * 2][q15][0], al0);                                    \
    softmax_slab(S1, (KB) == 2 * qs + 1, r0 + 64, (KB), g, q15, m21, l1,       \
                 &Psm[w * 2 + 1][q15][0], al1);                                \
    _Pragma("unroll") for (int dv = 0; dv < 4; ++dv) {                         \
      oa0[dv][0] *= al0[0]; oa0[dv][1] *= al0[1];                              \
      oa0[dv][2] *= al0[2]; oa0[dv][3] *= al0[3];                              \
      oa1[dv][0] *= al1[0]; oa1[dv][1] *= al1[1];                              \
      oa1[dv][2] *= al1[2]; oa1[dv][3] *= al1[3];                              \
    }                                                                          \
    LGKM0();                                                                   \
    _Pragma("unroll") for (int half = 0; half < 2; ++half) {                   \
      const bf16x8 pa0 = *(const bf16x8*)(&Psm[w * 2][q15][half * 32 + 8 * g]); \
      const bf16x8 pa1 = *(const bf16x8*)(&Psm[w * 2 + 1][q15][half * 32 + 8 * g]); \
      _Pragma("unroll") for (int dv = 0; dv < 4; ++dv) {                       \
        const int row = dv * 16 + q15;                                         \
        const bf16x8 vb = *(const bf16x8*)((Vb) + row * 64 + (((half * 4 + g) ^ (row & 7)) * 8)); \
        oa0[dv] = MFMA_(pa0, vb, oa0[dv], 0, 0, 0);                            \
        oa1[dv] = MFMA_(pa1, vb, oa1[dv], 0, 0, 0);                            \
      }                                                                        \
    }                                                                          \
  } while (0)

__global__ __launch_bounds__(256, 2) void attn_kernel(const u16* __restrict__ qk,
                                                      const u16* __restrict__ vT,
                                                      u16* __restrict__ o) {
  __shared__ __align__(16) u16 Ksm[3][4096];
  __shared__ __align__(16) u16 Vsm[3][4096];
  __shared__ __align__(16) u16 Psm[8][16][72];
  const int lid = blockIdx.x;
  const int xcd = lid & 7, s6 = lid >> 3;
  const int b2 = (s6 >> 4) & 3, xr = s6 & 15;
  const int qs = (b2 & 2) ? (15 - xr) : xr;
  const int bh = xcd + 8 * b2;
  const int b = bh >> 4, h = bh & 15;
  const int tid = threadIdx.x, lane = tid & 63, w = tid >> 6;
  const int q15 = lane & 15, g = lane >> 4;
  const u16* qbase = qk + (long)b * 2048 * 2048 + h * 64;
  const u16* kbase = qbase + 1024;
  const u16* vtb = vT + (long)bh * 64 * 2048;
  f32x4 zero4 = {0.f, 0.f, 0.f, 0.f};

  const int r0 = qs * 128 + w * 16 + q15;
  bf16x8 qa[2][2];
  qa[0][0] = *(const bf16x8*)(qbase + (long)r0 * 2048 + g * 8);
  qa[0][1] = *(const bf16x8*)(qbase + (long)r0 * 2048 + 32 + g * 8);
  qa[1][0] = *(const bf16x8*)(qbase + (long)(r0 + 64) * 2048 + g * 8);
  qa[1][1] = *(const bf16x8*)(qbase + (long)(r0 + 64) * 2048 + 32 + g * 8);

  f32x4 oa0[4], oa1[4];
#pragma unroll
  for (int dv = 0; dv < 4; ++dv) { oa0[dv] = zero4; oa1[dv] = zero4; }
  float m20 = -1e30f, l0 = 0.f, m21 = -1e30f, l1 = 0.f;
  const int kbmax = 2 * qs + 1;   // >= 1; tile count kbmax+1 is even

  // prologue: stage tiles 0 and 1; wait tile 0 only; QK(0) -> sA
  attn_stage(kbase, vtb, 0, Ksm[0], Vsm[0], tid);
  attn_stage(kbase, vtb, 1, Ksm[1], Vsm[1], tid);
  asm volatile("s_waitcnt vmcnt(4)" ::: "memory");
  __builtin_amdgcn_sched_barrier(0);
  __syncthreads();
  f32x4 sA0[4], sA1[4], sB0[4], sB1[4];
  QKCOMP(sA0, sA1, Ksm[0]);

  for (int t = 0; t <= kbmax; t += 2) {
    // ---- even half: tile t from sA; QK(t+1) overlaps softmax/PV(t) ----
    VMC0();              // own stage(t+1) landed
    __syncthreads();     // all waves' stage(t+1) landed; all past PV(t-1)
    if (t + 2 <= kbmax)
      attn_stage(kbase, vtb, t + 2, Ksm[(t + 2) % 3], Vsm[(t + 2) % 3], tid);
    QKCOMP(sB0, sB1, Ksm[(t + 1) % 3]);
    SMPV(sA0, sA1, t, Vsm[t % 3]);
    // ---- odd half: tile t+1 from sB; QK(t+2) overlaps ----
    VMC0();
    __syncthreads();
    if (t + 3 <= kbmax)
      attn_stage(kbase, vtb, t + 3, Ksm[(t + 3) % 3], Vsm[(t + 3) % 3], tid);
    if (t + 2 <= kbmax) QKCOMP(sA0, sA1, Ksm[(t + 2) % 3]);
    SMPV(sB0, sB1, t + 1, Vsm[(t + 1) % 3]);
  }

  const float li0 = 1.0f / l0, li1 = 1.0f / l1;
  float v0[4], v1[4];
#pragma unroll
  for (int r = 0; r < 4; ++r) {
    v0[r] = __shfl(li0, 4 * g + r);
    v1[r] = __shfl(li1, 4 * g + r);
  }
  const int tok0 = b * 2048 + qs * 128 + w * 16;
#pragma unroll
  for (int dv = 0; dv < 4; ++dv)
#pragma unroll
    for (int r = 0; r < 4; ++r) {
      o[(long)(tok0 + 4 * g + r) * 1024 + h * 64 + dv * 16 + q15] =
          f2bf(oa0[dv][r] * v0[r]);
      o[(long)(tok0 + 64 + 4 * g + r) * 1024 + h * 64 + dv * 16 + q15] =
          f2bf(oa1[dv][r] * v1[r]);
    }
}

extern "C" void kernel_launch(void* const* d_in, const int* in_sizes, int n_in,
                              void* d_out, int out_size, void* d_ws, size_t ws_size,
                              hipStream_t stream) {
  (void)in_sizes; (void)n_in; (void)out_size; (void)ws_size;
  const float* x  = (const float*)d_in[0];
  const float* Wq = (const float*)d_in[1];
  const float* bq = (const float*)d_in[2];
  const float* Wk = (const float*)d_in[3];
  const float* bk = (const float*)d_in[4];
  const float* Wv = (const float*)d_in[5];
  const float* bv = (const float*)d_in[6];
  const float* Wo = (const float*)d_in[7];
  const float* bo = (const float*)d_in[8];
  const float* g1 = (const float*)d_in[9];
  const float* be1 = (const float*)d_in[10];
  const float* g2 = (const float*)d_in[11];
  const float* be2 = (const float*)d_in[12];
  const float* W1 = (const float*)d_in[13];
  const float* b1 = (const float*)d_in[14];
  const float* W2 = (const float*)d_in[15];
  const float* b2 = (const float*)d_in[16];

  char* ws = (char*)d_ws;
  u16*   xn_bf = (u16*)  (ws + 0);          // LN1 out bf16 (GEMM A + residual)
  u16*   WqkvT = (u16*)  (ws + 25165824);
  u16*   WoT   = (u16*)  (ws + 31457280);
  u16*   W1T   = (u16*)  (ws + 33554432);
  u16*   W2T   = (u16*)  (ws + 41943040);
  u16*   qkb   = (u16*)  (ws + 50331648);
  u16*   vTb   = (u16*)  (ws + 67108864);
  u16*   ah    = (u16*)  (ws + 75497472);
  u16*   pwo0  = (u16*)  (ws + 50331648);   // Wo partials (qkb dead after attn)
  u16*   gbuf  = (u16*)  (ws + 50331648);   // FFN hidden 32MB (dead region)
  u16*   part  = (u16*)  (ws + 8388608);    // FFN2 partials 2x8MB
  u16*   yn_bf = (u16*)  (ws + 83886080);   // LN2 out bf16 (GEMM A + residual)

  dim3 tb(32, 8), b256(256);
  wprep_kernel<<<dim3(16384), tb, 0, stream>>>(Wq, Wk, Wv, Wo, W1, W2,
                                               WqkvT, WoT, W1T, W2T,
                                               x, g1, be1, xn_bf);
  gemm128_kernel<0><<<dim3(32, 24, 1), b256, 0, stream>>>(xn_bf, WqkvT, 1024, 16, 3072,
                                                          bq, bk, bv, qkb, vTb);
  attn_kernel<<<dim3(512), b256, 0, stream>>>(qkb, vTb, ah);
  gemm128_kernel<5><<<dim3(32, 8, 2), b256, 0, stream>>>(ah, WoT, 1024, 8, 1024,
                                                         nullptr, nullptr, nullptr, pwo0, nullptr);
  ln2_fused_kernel<<<dim3(4096), b256, 0, stream>>>(pwo0, pwo0 + 4194304, bo, xn_bf,
                                                    g2, be2, yn_bf);
  gemm128_kernel<2><<<dim3(32, 32, 1), b256, 0, stream>>>(yn_bf, W1T, 1024, 16, 4096,
                                                          b1, nullptr, nullptr, gbuf, nullptr);
  gemm128_kernel<5><<<dim3(32, 8, 2), b256, 0, stream>>>(gbuf, W2T, 4096, 32, 1024,
                                                         nullptr, nullptr, nullptr, part, nullptr);
  ffn2_reduce_kernel<<<dim3(4096), b256, 0, stream>>>(part, b2, yn_bf, (float*)d_out);
}

// Round 15
// 210.567 us; speedup vs baseline: 1.0292x; 1.0292x over previous
//
#include <hip/hip_runtime.h>

typedef unsigned short u16;
typedef unsigned int u32;
typedef __attribute__((ext_vector_type(8))) short bf16x8;
typedef __attribute__((ext_vector_type(4))) float f32x4;

#define AS1 __attribute__((address_space(1)))
#define AS3 __attribute__((address_space(3)))

__device__ __forceinline__ u16 f2bf(float f) {
  u32 u = __float_as_uint(f);
  u = (u + 0x7fffu + ((u >> 16) & 1u)) >> 16;
  return (u16)u;
}
__device__ __forceinline__ float bf2f(u16 v) { return __uint_as_float((u32)v << 16); }

__device__ __forceinline__ void gl16(const void* g, void* l) {
  __builtin_amdgcn_global_load_lds((AS1 void*)g, (AS3 void*)l, 16, 0, 0);
}

__device__ __forceinline__ float exp2a(float x) {
  float r;
  asm("v_exp_f32 %0, %1" : "=v"(r) : "v"(x));
  return r;
}
__device__ __forceinline__ u32 pk2(float lo, float hi) {
  u32 r;
  asm("v_cvt_pk_bf16_f32 %0, %1, %2" : "=v"(r) : "v"(lo), "v"(hi));
  return r;
}

#define LGKM0()                                         \
  do {                                                  \
    asm volatile("s_waitcnt lgkmcnt(0)" ::: "memory");  \
    __builtin_amdgcn_sched_barrier(0);                  \
  } while (0)
#define VMC0()                                          \
  do {                                                  \
    asm volatile("s_waitcnt vmcnt(0)" ::: "memory");    \
    __builtin_amdgcn_sched_barrier(0);                  \
  } while (0)

// ---- merged prep: weight transposes + LN1, one launch ----------------------
__global__ __launch_bounds__(256) void wprep_kernel(
    const float* __restrict__ Wq, const float* __restrict__ Wk,
    const float* __restrict__ Wv, const float* __restrict__ Wo,
    const float* __restrict__ W1, const float* __restrict__ W2,
    u16* __restrict__ WqkvT, u16* __restrict__ WoT,
    u16* __restrict__ W1T, u16* __restrict__ W2T,
    const float* __restrict__ x, const float* __restrict__ gamma,
    const float* __restrict__ beta, u16* __restrict__ xn_bf) {
  __shared__ float tile[32][33];
  __shared__ float rs[4], rq[4];
  int id = blockIdx.x;
  const int tx = threadIdx.x, ty = threadIdx.y;
  if (id >= 12288) {
    const int row = id - 12288;
    const int tid = ty * 32 + tx;
    const float* xr = x + (long)row * 1024;
    float4 v = *(const float4*)(xr + tid * 4);
    float s = v.x + v.y + v.z + v.w;
    float sq = v.x * v.x + v.y * v.y + v.z * v.z + v.w * v.w;
#pragma unroll
    for (int off = 1; off < 64; off <<= 1) {
      s += __shfl_xor(s, off);
      sq += __shfl_xor(sq, off);
    }
    const int w = tid >> 6, lane = tid & 63;
    if (lane == 0) { rs[w] = s; rq[w] = sq; }
    __syncthreads();
    s = rs[0] + rs[1] + rs[2] + rs[3];
    sq = rq[0] + rq[1] + rq[2] + rq[3];
    const float mean = s * (1.0f / 1024.0f);
    const float var = (sq - 1024.0f * mean * mean) * (1.0f / 1023.0f);
    const float rstd = rsqrtf(var + 1e-5f);
    float4 g4 = *(const float4*)(gamma + tid * 4);
    float4 b4 = *(const float4*)(beta + tid * 4);
    ushort4 ub;
    ub.x = f2bf((v.x - mean) * rstd * g4.x + b4.x);
    ub.y = f2bf((v.y - mean) * rstd * g4.y + b4.y);
    ub.z = f2bf((v.z - mean) * rstd * g4.z + b4.z);
    ub.w = f2bf((v.w - mean) * rstd * g4.w + b4.w);
    *(ushort4*)(xn_bf + (long)row * 1024 + tid * 4) = ub;
    return;
  }
  const float* ip;
  u16* op;
  int in_rs, R, c0, r0;
  if (id < 3072) {
    const int xq = id & 1, y = (id >> 1) & 31, z = id >> 6;
    const float* in = z < 16 ? Wq : (z < 32 ? Wk : Wv);
    ip = in + (long)(z & 15) * 65536;
    op = WqkvT + (long)z * 65536;
    in_rs = 64; R = 1024; c0 = xq * 32; r0 = y * 32;
  } else if (id < 4096) {
    id -= 3072;
    ip = Wo; op = WoT; in_rs = 1024; R = 1024;
    c0 = (id & 31) * 32; r0 = (id >> 5) * 32;
  } else if (id < 8192) {
    id -= 4096;
    ip = W1; op = W1T; in_rs = 4096; R = 1024;
    c0 = (id & 127) * 32; r0 = (id >> 7) * 32;
  } else {
    id -= 8192;
    ip = W2; op = W2T; in_rs = 1024; R = 4096;
    c0 = (id & 31) * 32; r0 = (id >> 5) * 32;
  }
#pragma unroll
  for (int i = 0; i < 4; ++i)
    tile[ty + i * 8][tx] = ip[(long)(r0 + ty + i * 8) * in_rs + c0 + tx];
  __syncthreads();
#pragma unroll
  for (int i = 0; i < 4; ++i)
    op[(long)(c0 + ty + i * 8) * R + r0 + tx] = f2bf(tile[tx][ty + i * 8]);
}

// ---- fused LN2: y = p0+p1+bo+xn_bf (bf16 residual), then layernorm ----------
__global__ __launch_bounds__(256) void ln2_fused_kernel(
    const u16* __restrict__ p0, const u16* __restrict__ p1,
    const float* __restrict__ bo, const u16* __restrict__ xnbf,
    const float* __restrict__ gamma, const float* __restrict__ beta,
    u16* __restrict__ obf) {
  const int row = blockIdx.x;
  const int tid = threadIdx.x;
  const long i4 = (long)row * 1024 + tid * 4;
  ushort4 a0 = *(const ushort4*)(p0 + i4);
  ushort4 a1 = *(const ushort4*)(p1 + i4);
  ushort4 xv = *(const ushort4*)(xnbf + i4);
  float4 bv = *(const float4*)(bo + tid * 4);
  float y0 = bf2f(a0.x) + bf2f(a1.x) + bv.x + bf2f(xv.x);
  float y1 = bf2f(a0.y) + bf2f(a1.y) + bv.y + bf2f(xv.y);
  float y2 = bf2f(a0.z) + bf2f(a1.z) + bv.z + bf2f(xv.z);
  float y3 = bf2f(a0.w) + bf2f(a1.w) + bv.w + bf2f(xv.w);
  float s = y0 + y1 + y2 + y3;
  float sq = y0 * y0 + y1 * y1 + y2 * y2 + y3 * y3;
#pragma unroll
  for (int off = 1; off < 64; off <<= 1) {
    s += __shfl_xor(s, off);
    sq += __shfl_xor(sq, off);
  }
  __shared__ float rs[4], rq[4];
  const int w = tid >> 6, lane = tid & 63;
  if (lane == 0) { rs[w] = s; rq[w] = sq; }
  __syncthreads();
  s = rs[0] + rs[1] + rs[2] + rs[3];
  sq = rq[0] + rq[1] + rq[2] + rq[3];
  const float mean = s * (1.0f / 1024.0f);
  const float var = (sq - 1024.0f * mean * mean) * (1.0f / 1023.0f);
  const float rstd = rsqrtf(var + 1e-5f);
  float4 g4 = *(const float4*)(gamma + tid * 4);
  float4 b4 = *(const float4*)(beta + tid * 4);
  ushort4 ub;
  ub.x = f2bf((y0 - mean) * rstd * g4.x + b4.x);
  ub.y = f2bf((y1 - mean) * rstd * g4.y + b4.y);
  ub.z = f2bf((y2 - mean) * rstd * g4.z + b4.z);
  ub.w = f2bf((y3 - mean) * rstd * g4.w + b4.w);
  *(ushort4*)(obf + i4) = ub;
}

// ---- FFN2 split-K=2 reduce: out = p0+p1 + b2 + yn_bf (bf16 residual) --------
__global__ __launch_bounds__(256) void ffn2_reduce_kernel(const u16* __restrict__ p,
                                                          const float* __restrict__ b2,
                                                          const u16* __restrict__ ynbf,
                                                          float* __restrict__ out) {
  const long i4 = ((long)blockIdx.x * 256 + threadIdx.x) * 4;
  ushort4 p0 = *(const ushort4*)(p + i4);
  ushort4 p1 = *(const ushort4*)(p + 4194304 + i4);
  ushort4 rr = *(const ushort4*)(ynbf + i4);
  const int nn = (int)(i4 & 1023);
  float4 bb = *(const float4*)(b2 + nn);
  float4 o;
  o.x = bf2f(p0.x) + bf2f(p1.x) + bb.x + bf2f(rr.x);
  o.y = bf2f(p0.y) + bf2f(p1.y) + bb.y + bf2f(rr.y);
  o.z = bf2f(p0.z) + bf2f(p1.z) + bb.z + bf2f(rr.z);
  o.w = bf2f(p0.w) + bf2f(p1.w) + bb.w + bf2f(rr.w);
  *(float4*)(out + i4) = o;
}

// ====== 128x128 bf16 GEMM (m97-class) =======================================
template <int EPI>
__global__ __launch_bounds__(256, 2) void gemm128_kernel(
    const u16* __restrict__ A, const u16* __restrict__ Bt,
    int K, int nk, int N,
    const float* bias0, const float* bias1, const float* bias2,
    void* out0, void* out1) {
  __shared__ __align__(16) u16 Asm[128 * 64];
  __shared__ __align__(16) u16 Bsm[128 * 64];
  const int tid = threadIdx.x;
  const int lane = tid & 63, w = tid >> 6;
  const int wm = w >> 1, wn = w & 1;
  const int q = lane & 15, g = lane >> 4;
  const long m0 = (long)blockIdx.x * 128;
  const long n0 = (long)blockIdx.y * 128;
  const int bz = blockIdx.z;
  const long koff = (long)bz * (long)nk * 64;

  f32x4 zero4 = {0.f, 0.f, 0.f, 0.f};
  f32x4 acc[4][4];
#pragma unroll
  for (int mi = 0; mi < 4; ++mi)
#pragma unroll
    for (int ni = 0; ni < 4; ++ni) acc[mi][ni] = zero4;

  for (int ks = 0; ks < nk; ++ks) {
    __syncthreads();
    const u16* ga = A + m0 * K + koff + ks * 64;
    const u16* gb = Bt + n0 * K + koff + ks * 64;
    const int base = w * 256;
#pragma unroll
    for (int i = 0; i < 4; ++i) {
      const int idx = base + i * 64 + lane;
      const int row = idx >> 3;
      const int lg = (idx & 7) ^ (row & 7);
      gl16(ga + (long)row * K + lg * 8, Asm + (long)(base + i * 64) * 8);
    }
#pragma unroll
    for (int i = 0; i < 4; ++i) {
      const int idx = base + i * 64 + lane;
      const int row = idx >> 3;
      const int lg = (idx & 7) ^ (row & 7);
      gl16(gb + (long)row * K + lg * 8, Bsm + (long)(base + i * 64) * 8);
    }
    __syncthreads();
#pragma unroll
    for (int half = 0; half < 2; ++half) {
      bf16x8 af[4], bfv[4];
#pragma unroll
      for (int mi = 0; mi < 4; ++mi) {
        const int row = wm * 64 + mi * 16 + q;
        const int ph = (half * 4 + g) ^ (row & 7);
        af[mi] = *(const bf16x8*)(Asm + row * 64 + ph * 8);
      }
#pragma unroll
      for (int ni = 0; ni < 4; ++ni) {
        const int row = wn * 64 + ni * 16 + q;
        const int ph = (half * 4 + g) ^ (row & 7);
        bfv[ni] = *(const bf16x8*)(Bsm + row * 64 + ph * 8);
      }
#pragma unroll
      for (int mi = 0; mi < 4; ++mi)
#pragma unroll
        for (int ni = 0; ni < 4; ++ni)
          acc[mi][ni] = __builtin_amdgcn_mfma_f32_16x16x32_bf16(af[mi], bfv[ni],
                                                                acc[mi][ni], 0, 0, 0);
    }
  }
#pragma unroll
  for (int mi = 0; mi < 4; ++mi) {
#pragma unroll
    for (int ni = 0; ni < 4; ++ni) {
      const long mbase = m0 + wm * 64 + mi * 16 + 4 * g;
      const long n = n0 + wn * 64 + ni * 16 + q;
      f32x4 a = acc[mi][ni];
      if constexpr (EPI == 0) {
        const int sel = (int)(n >> 10);
        const int nn = (int)(n & 1023);
        const float* bp = sel == 0 ? bias0 : (sel == 1 ? bias1 : bias2);
        const float bb2 = bp[nn];
        if (sel < 2) {
          const float sc = (sel == 0) ? 0.18033688011112043f : 1.0f;
          u16* qkp = (u16*)out0;
#pragma unroll
          for (int r = 0; r < 4; ++r)
            qkp[(mbase + r) * 2048 + n] = f2bf((a[r] + bb2) * sc);
        } else {
          const int bI = (int)(mbase >> 11);
          const int t = (int)(mbase & 2047);
          const int hh = nn >> 6, dh = nn & 63;
          ushort4 pk;
          pk.x = f2bf(a[0] + bb2); pk.y = f2bf(a[1] + bb2);
          pk.z = f2bf(a[2] + bb2); pk.w = f2bf(a[3] + bb2);
          *(ushort4*)((u16*)out1 + ((long)((bI * 16 + hh) * 64 + dh)) * 2048 + t) = pk;
        }
      } else if constexpr (EPI == 2) {
        u16* gp = (u16*)out0;
        const float bb2 = bias0[(int)n];
#pragma unroll
        for (int r = 0; r < 4; ++r) {
          const float xg = a[r] + bb2;
          const float ge = 0.5f * xg * (1.0f + erff(xg * 0.70710678118f));
          gp[(mbase + r) * N + n] = f2bf(ge);
        }
      } else {  // EPI == 5: bf16 partial per K-slice
        u16* pp = (u16*)out0 + (long)bz * 4096 * 1024;
#pragma unroll
        for (int r = 0; r < 4; ++r) pp[(mbase + r) * 1024 + n] = f2bf(a[r]);
      }
    }
  }
}

// --------- causal flash attention (R8 body) + T13 defer-max ------------------
__device__ __forceinline__ void attn_stage(const u16* kbase, const u16* vtb, int kb,
                                           u16* Kd, u16* Vd, int tid) {
#pragma unroll
  for (int it = 0; it < 2; ++it) {
    const int gi = it * 256 + tid;
    const int row = gi >> 3;
    const int lg = (gi & 7) ^ (row & 7);
    gl16(kbase + (long)(kb * 64 + row) * 2048 + lg * 8, Kd + gi * 8);
    gl16(vtb + (long)row * 2048 + kb * 64 + lg * 8, Vd + gi * 8);
  }
}

// returns true if rescale was SKIPPED (deferred); al valid only when false.
__device__ __forceinline__ bool softmax_slab(const f32x4 st[4], bool diag, int qrow,
                                             int kb, int g, int q15,
                                             float& m2, float& l, u16* prow,
                                             float al[4]) {
  float sv[4][4];
  float rmax = -1e30f;
#pragma unroll
  for (int sub = 0; sub < 4; ++sub)
#pragma unroll
    for (int r = 0; r < 4; ++r) {
      float s_ = st[sub][r];
      if (diag) {
        const int key = kb * 64 + sub * 16 + 4 * g + r;
        s_ = (key > qrow) ? -1e30f : s_;
      }
      sv[sub][r] = s_;
      rmax = fmaxf(rmax, s_);
    }
  rmax = fmaxf(rmax, __shfl_xor(rmax, 16));
  rmax = fmaxf(rmax, __shfl_xor(rmax, 32));
  // T13 defer-max: keep old max if tile max grew by <= 8 (exp2 domain):
  // P then bounded by 2^8, safe for f32 accum / bf16-P storage.
  const bool defer = (__all(rmax - m2 <= 8.0f) != 0);
  const float mnew = defer ? m2 : fmaxf(m2, rmax);
  float psum = 0.f;
#pragma unroll
  for (int sub = 0; sub < 4; ++sub) {
    const float p0 = exp2a(sv[sub][0] - mnew);
    const float p1 = exp2a(sv[sub][1] - mnew);
    const float p2 = exp2a(sv[sub][2] - mnew);
    const float p3 = exp2a(sv[sub][3] - mnew);
    uint2 u;
    u.x = pk2(p0, p1);
    u.y = pk2(p2, p3);
    *(uint2*)(prow + sub * 16 + 4 * g) = u;
    psum += (p0 + p1) + (p2 + p3);
  }
  psum += __shfl_xor(psum, 16);
  psum += __shfl_xor(psum, 32);
  if (defer) {
    l += psum;
  } else {
    const float alpha = exp2a(m2 - mnew);
    l = l * alpha + psum;
    m2 = mnew;
#pragma unroll
    for (int r = 0; r < 4; ++r) al[r] = __shfl(alpha, 4 * g + r);
  }
  return defer;
}

__global__ __launch_bounds__(256, 2) void attn_kernel(const u16* __restrict__ qk,
                                                      const u16* __restrict__ vT,
                                                      u16* __restrict__ o) {
  __shared__ __align__(16) u16 Ksm[2][64 * 64];
  __shared__ __align__(16) u16 Vsm[2][64 * 64];
  __shared__ __align__(16) u16 Psm[8][16][72];
  const int lid = blockIdx.x;
  const int xcd = lid & 7, s6 = lid >> 3;
  const int b2 = (s6 >> 4) & 3, xr = s6 & 15;
  const int qs = (b2 & 2) ? (15 - xr) : xr;
  const int bh = xcd + 8 * b2;
  const int b = bh >> 4, h = bh & 15;
  const int tid = threadIdx.x, lane = tid & 63, w = tid >> 6;
  const int q15 = lane & 15, g = lane >> 4;
  const u16* qbase = qk + (long)b * 2048 * 2048 + h * 64;
  const u16* kbase = qbase + 1024;
  const u16* vtb = vT + (long)bh * 64 * 2048;
  f32x4 zero4 = {0.f, 0.f, 0.f, 0.f};

  const int r0 = qs * 128 + w * 16 + q15;
  bf16x8 qa[2][2];
  qa[0][0] = *(const bf16x8*)(qbase + (long)r0 * 2048 + g * 8);
  qa[0][1] = *(const bf16x8*)(qbase + (long)r0 * 2048 + 32 + g * 8);
  qa[1][0] = *(const bf16x8*)(qbase + (long)(r0 + 64) * 2048 + g * 8);
  qa[1][1] = *(const bf16x8*)(qbase + (long)(r0 + 64) * 2048 + 32 + g * 8);

  f32x4 oa0[4], oa1[4];
#pragma unroll
  for (int dv = 0; dv < 4; ++dv) { oa0[dv] = zero4; oa1[dv] = zero4; }
  float m20 = -1e30f, l0 = 0.f, m21 = -1e30f, l1 = 0.f;
  const int kbmax = 2 * qs + 1;

  attn_stage(kbase, vtb, 0, Ksm[0], Vsm[0], tid);
  VMC0();
  __syncthreads();

  for (int kb = 0; kb <= kbmax; ++kb) {
    const int buf = kb & 1;
    if (kb < kbmax) attn_stage(kbase, vtb, kb + 1, Ksm[buf ^ 1], Vsm[buf ^ 1], tid);
    const u16* Kb = Ksm[buf];
    const u16* Vb = Vsm[buf];
    const bool s0on = (kb <= 2 * qs);
    f32x4 st0[4], st1[4];
#pragma unroll
    for (int sub = 0; sub < 4; ++sub) {
      const int row = sub * 16 + q15;
      const bf16x8 ka0 = *(const bf16x8*)(Kb + row * 64 + ((g ^ (row & 7)) * 8));
      const bf16x8 ka1 = *(const bf16x8*)(Kb + row * 64 + (((4 + g) ^ (row & 7)) * 8));
      f32x4 z = zero4;
      z = __builtin_amdgcn_mfma_f32_16x16x32_bf16(ka0, qa[1][0], z, 0, 0, 0);
      z = __builtin_amdgcn_mfma_f32_16x16x32_bf16(ka1, qa[1][1], z, 0, 0, 0);
      st1[sub] = z;
      if (s0on) {
        f32x4 z0 = zero4;
        z0 = __builtin_amdgcn_mfma_f32_16x16x32_bf16(ka0, qa[0][0], z0, 0, 0, 0);
        z0 = __builtin_amdgcn_mfma_f32_16x16x32_bf16(ka1, qa[0][1], z0, 0, 0, 0);
        st0[sub] = z0;
      }
    }
    float al0[4], al1[4];
    bool d0 = true, d1;
    if (s0on)
      d0 = softmax_slab(st0, kb == 2 * qs, r0, kb, g, q15, m20, l0,
                        &Psm[w * 2][q15][0], al0);
    d1 = softmax_slab(st1, kb == 2 * qs + 1, r0 + 64, kb, g, q15, m21, l1,
                      &Psm[w * 2 + 1][q15][0], al1);
    if (s0on && !d0)
#pragma unroll
      for (int dv = 0; dv < 4; ++dv) {
        oa0[dv][0] *= al0[0]; oa0[dv][1] *= al0[1];
        oa0[dv][2] *= al0[2]; oa0[dv][3] *= al0[3];
      }
    if (!d1)
#pragma unroll
      for (int dv = 0; dv < 4; ++dv) {
        oa1[dv][0] *= al1[0]; oa1[dv][1] *= al1[1];
        oa1[dv][2] *= al1[2]; oa1[dv][3] *= al1[3];
      }
    LGKM0();
#pragma unroll
    for (int half = 0; half < 2; ++half) {
      const bf16x8 pa0 = *(const bf16x8*)(&Psm[w * 2][q15][half * 32 + 8 * g]);
      const bf16x8 pa1 = *(const bf16x8*)(&Psm[w * 2 + 1][q15][half * 32 + 8 * g]);
#pragma unroll
      for (int dv = 0; dv < 4; ++dv) {
        const int row = dv * 16 + q15;
        const bf16x8 vb = *(const bf16x8*)(Vb + row * 64 + (((half * 4 + g) ^ (row & 7)) * 8));
        if (s0on) oa0[dv] = __builtin_amdgcn_mfma_f32_16x16x32_bf16(pa0, vb, oa0[dv], 0, 0, 0);
        oa1[dv] = __builtin_amdgcn_mfma_f32_16x16x32_bf16(pa1, vb, oa1[dv], 0, 0, 0);
      }
    }
    VMC0();
    __syncthreads();
  }
  const float li0 = 1.0f / l0, li1 = 1.0f / l1;
  float v0[4], v1[4];
#pragma unroll
  for (int r = 0; r < 4; ++r) {
    v0[r] = __shfl(li0, 4 * g + r);
    v1[r] = __shfl(li1, 4 * g + r);
  }
  const int tok0 = b * 2048 + qs * 128 + w * 16;
#pragma unroll
  for (int dv = 0; dv < 4; ++dv)
#pragma unroll
    for (int r = 0; r < 4; ++r) {
      o[(long)(tok0 + 4 * g + r) * 1024 + h * 64 + dv * 16 + q15] =
          f2bf(oa0[dv][r] * v0[r]);
      o[(long)(tok0 + 64 + 4 * g + r) * 1024 + h * 64 + dv * 16 + q15] =
          f2bf(oa1[dv][r] * v1[r]);
    }
}

extern "C" void kernel_launch(void* const* d_in, const int* in_sizes, int n_in,
                              void* d_out, int out_size, void* d_ws, size_t ws_size,
                              hipStream_t stream) {
  (void)in_sizes; (void)n_in; (void)out_size; (void)ws_size;
  const float* x  = (const float*)d_in[0];
  const float* Wq = (const float*)d_in[1];
  const float* bq = (const float*)d_in[2];
  const float* Wk = (const float*)d_in[3];
  const float* bk = (const float*)d_in[4];
  const float* Wv = (const float*)d_in[5];
  const float* bv = (const float*)d_in[6];
  const float* Wo = (const float*)d_in[7];
  const float* bo = (const float*)d_in[8];
  const float* g1 = (const float*)d_in[9];
  const float* be1 = (const float*)d_in[10];
  const float* g2 = (const float*)d_in[11];
  const float* be2 = (const float*)d_in[12];
  const float* W1 = (const float*)d_in[13];
  const float* b1 = (const float*)d_in[14];
  const float* W2 = (const float*)d_in[15];
  const float* b2 = (const float*)d_in[16];

  char* ws = (char*)d_ws;
  u16*   xn_bf = (u16*)  (ws + 0);          // LN1 out bf16 (GEMM A + residual)
  u16*   WqkvT = (u16*)  (ws + 25165824);
  u16*   WoT   = (u16*)  (ws + 31457280);
  u16*   W1T   = (u16*)  (ws + 33554432);
  u16*   W2T   = (u16*)  (ws + 41943040);
  u16*   qkb   = (u16*)  (ws + 50331648);
  u16*   vTb   = (u16*)  (ws + 67108864);
  u16*   ah    = (u16*)  (ws + 75497472);
  u16*   pwo0  = (u16*)  (ws + 50331648);   // Wo partials (qkb dead after attn)
  u16*   gbuf  = (u16*)  (ws + 50331648);   // FFN hidden 32MB (dead region)
  u16*   part  = (u16*)  (ws + 8388608);    // FFN2 partials 2x8MB
  u16*   yn_bf = (u16*)  (ws + 83886080);   // LN2 out bf16 (GEMM A + residual)

  dim3 tb(32, 8), b256(256);
  wprep_kernel<<<dim3(16384), tb, 0, stream>>>(Wq, Wk, Wv, Wo, W1, W2,
                                               WqkvT, WoT, W1T, W2T,
                                               x, g1, be1, xn_bf);
  gemm128_kernel<0><<<dim3(32, 24, 1), b256, 0, stream>>>(xn_bf, WqkvT, 1024, 16, 3072,
                                                          bq, bk, bv, qkb, vTb);
  attn_kernel<<<dim3(512), b256, 0, stream>>>(qkb, vTb, ah);
  gemm128_kernel<5><<<dim3(32, 8, 2), b256, 0, stream>>>(ah, WoT, 1024, 8, 1024,
                                                         nullptr, nullptr, nullptr, pwo0, nullptr);
  ln2_fused_kernel<<<dim3(4096), b256, 0, stream>>>(pwo0, pwo0 + 4194304, bo, xn_bf,
                                                    g2, be2, yn_bf);
  gemm128_kernel<2><<<dim3(32, 32, 1), b256, 0, stream>>>(yn_bf, W1T, 1024, 16, 4096,
                                                          b1, nullptr, nullptr, gbuf, nullptr);
  gemm128_kernel<5><<<dim3(32, 8, 2), b256, 0, stream>>>(gbuf, W2T, 4096, 32, 1024,
                                                         nullptr, nullptr, nullptr, part, nullptr);
  ffn2_reduce_kernel<<<dim3(4096), b256, 0, stream>>>(part, b2, yn_bf, (float*)d_out);
}

// Round 16
// 208.655 us; speedup vs baseline: 1.0386x; 1.0092x over previous
//
#include <hip/hip_runtime.h>

typedef unsigned short u16;
typedef unsigned int u32;
typedef __attribute__((ext_vector_type(8))) short bf16x8;
typedef __attribute__((ext_vector_type(4))) float f32x4;

#define AS1 __attribute__((address_space(1)))
#define AS3 __attribute__((address_space(3)))

__device__ __forceinline__ u16 f2bf(float f) {
  u32 u = __float_as_uint(f);
  u = (u + 0x7fffu + ((u >> 16) & 1u)) >> 16;
  return (u16)u;
}
__device__ __forceinline__ float bf2f(u16 v) { return __uint_as_float((u32)v << 16); }

__device__ __forceinline__ void gl16(const void* g, void* l) {
  __builtin_amdgcn_global_load_lds((AS1 void*)g, (AS3 void*)l, 16, 0, 0);
}

__device__ __forceinline__ float exp2a(float x) {
  float r;
  asm("v_exp_f32 %0, %1" : "=v"(r) : "v"(x));
  return r;
}
__device__ __forceinline__ u32 pk2(float lo, float hi) {
  u32 r;
  asm("v_cvt_pk_bf16_f32 %0, %1, %2" : "=v"(r) : "v"(lo), "v"(hi));
  return r;
}

#define LGKM0()                                         \
  do {                                                  \
    asm volatile("s_waitcnt lgkmcnt(0)" ::: "memory");  \
    __builtin_amdgcn_sched_barrier(0);                  \
  } while (0)
#define VMC0()                                          \
  do {                                                  \
    asm volatile("s_waitcnt vmcnt(0)" ::: "memory");    \
    __builtin_amdgcn_sched_barrier(0);                  \
  } while (0)

// ---- merged prep: weight transposes + LN1, one launch ----------------------
__global__ __launch_bounds__(256) void wprep_kernel(
    const float* __restrict__ Wq, const float* __restrict__ Wk,
    const float* __restrict__ Wv, const float* __restrict__ Wo,
    const float* __restrict__ W1, const float* __restrict__ W2,
    u16* __restrict__ WqkvT, u16* __restrict__ WoT,
    u16* __restrict__ W1T, u16* __restrict__ W2T,
    const float* __restrict__ x, const float* __restrict__ gamma,
    const float* __restrict__ beta, u16* __restrict__ xn_bf) {
  __shared__ float tile[32][33];
  __shared__ float rs[4], rq[4];
  int id = blockIdx.x;
  const int tx = threadIdx.x, ty = threadIdx.y;
  if (id >= 12288) {
    const int row = id - 12288;
    const int tid = ty * 32 + tx;
    const float* xr = x + (long)row * 1024;
    float4 v = *(const float4*)(xr + tid * 4);
    float s = v.x + v.y + v.z + v.w;
    float sq = v.x * v.x + v.y * v.y + v.z * v.z + v.w * v.w;
#pragma unroll
    for (int off = 1; off < 64; off <<= 1) {
      s += __shfl_xor(s, off);
      sq += __shfl_xor(sq, off);
    }
    const int w = tid >> 6, lane = tid & 63;
    if (lane == 0) { rs[w] = s; rq[w] = sq; }
    __syncthreads();
    s = rs[0] + rs[1] + rs[2] + rs[3];
    sq = rq[0] + rq[1] + rq[2] + rq[3];
    const float mean = s * (1.0f / 1024.0f);
    const float var = (sq - 1024.0f * mean * mean) * (1.0f / 1023.0f);
    const float rstd = rsqrtf(var + 1e-5f);
    float4 g4 = *(const float4*)(gamma + tid * 4);
    float4 b4 = *(const float4*)(beta + tid * 4);
    ushort4 ub;
    ub.x = f2bf((v.x - mean) * rstd * g4.x + b4.x);
    ub.y = f2bf((v.y - mean) * rstd * g4.y + b4.y);
    ub.z = f2bf((v.z - mean) * rstd * g4.z + b4.z);
    ub.w = f2bf((v.w - mean) * rstd * g4.w + b4.w);
    *(ushort4*)(xn_bf + (long)row * 1024 + tid * 4) = ub;
    return;
  }
  const float* ip;
  u16* op;
  int in_rs, R, c0, r0;
  if (id < 3072) {
    const int xq = id & 1, y = (id >> 1) & 31, z = id >> 6;
    const float* in = z < 16 ? Wq : (z < 32 ? Wk : Wv);
    ip = in + (long)(z & 15) * 65536;
    op = WqkvT + (long)z * 65536;
    in_rs = 64; R = 1024; c0 = xq * 32; r0 = y * 32;
  } else if (id < 4096) {
    id -= 3072;
    ip = Wo; op = WoT; in_rs = 1024; R = 1024;
    c0 = (id & 31) * 32; r0 = (id >> 5) * 32;
  } else if (id < 8192) {
    id -= 4096;
    ip = W1; op = W1T; in_rs = 4096; R = 1024;
    c0 = (id & 127) * 32; r0 = (id >> 7) * 32;
  } else {
    id -= 8192;
    ip = W2; op = W2T; in_rs = 1024; R = 4096;
    c0 = (id & 31) * 32; r0 = (id >> 5) * 32;
  }
#pragma unroll
  for (int i = 0; i < 4; ++i)
    tile[ty + i * 8][tx] = ip[(long)(r0 + ty + i * 8) * in_rs + c0 + tx];
  __syncthreads();
#pragma unroll
  for (int i = 0; i < 4; ++i)
    op[(long)(c0 + ty + i * 8) * R + r0 + tx] = f2bf(tile[tx][ty + i * 8]);
}

// ---- fused LN2: y = p0+p1+bo+xn_bf (bf16 residual), then layernorm ----------
__global__ __launch_bounds__(256) void ln2_fused_kernel(
    const u16* __restrict__ p0, const u16* __restrict__ p1,
    const float* __restrict__ bo, const u16* __restrict__ xnbf,
    const float* __restrict__ gamma, const float* __restrict__ beta,
    u16* __restrict__ obf) {
  const int row = blockIdx.x;
  const int tid = threadIdx.x;
  const long i4 = (long)row * 1024 + tid * 4;
  ushort4 a0 = *(const ushort4*)(p0 + i4);
  ushort4 a1 = *(const ushort4*)(p1 + i4);
  ushort4 xv = *(const ushort4*)(xnbf + i4);
  float4 bv = *(const float4*)(bo + tid * 4);
  float y0 = bf2f(a0.x) + bf2f(a1.x) + bv.x + bf2f(xv.x);
  float y1 = bf2f(a0.y) + bf2f(a1.y) + bv.y + bf2f(xv.y);
  float y2 = bf2f(a0.z) + bf2f(a1.z) + bv.z + bf2f(xv.z);
  float y3 = bf2f(a0.w) + bf2f(a1.w) + bv.w + bf2f(xv.w);
  float s = y0 + y1 + y2 + y3;
  float sq = y0 * y0 + y1 * y1 + y2 * y2 + y3 * y3;
#pragma unroll
  for (int off = 1; off < 64; off <<= 1) {
    s += __shfl_xor(s, off);
    sq += __shfl_xor(sq, off);
  }
  __shared__ float rs[4], rq[4];
  const int w = tid >> 6, lane = tid & 63;
  if (lane == 0) { rs[w] = s; rq[w] = sq; }
  __syncthreads();
  s = rs[0] + rs[1] + rs[2] + rs[3];
  sq = rq[0] + rq[1] + rq[2] + rq[3];
  const float mean = s * (1.0f / 1024.0f);
  const float var = (sq - 1024.0f * mean * mean) * (1.0f / 1023.0f);
  const float rstd = rsqrtf(var + 1e-5f);
  float4 g4 = *(const float4*)(gamma + tid * 4);
  float4 b4 = *(const float4*)(beta + tid * 4);
  ushort4 ub;
  ub.x = f2bf((y0 - mean) * rstd * g4.x + b4.x);
  ub.y = f2bf((y1 - mean) * rstd * g4.y + b4.y);
  ub.z = f2bf((y2 - mean) * rstd * g4.z + b4.z);
  ub.w = f2bf((y3 - mean) * rstd * g4.w + b4.w);
  *(ushort4*)(obf + i4) = ub;
}

// ---- FFN2 split-K=2 reduce: out = p0+p1 + b2 + yn_bf (bf16 residual) --------
__global__ __launch_bounds__(256) void ffn2_reduce_kernel(const u16* __restrict__ p,
                                                          const float* __restrict__ b2,
                                                          const u16* __restrict__ ynbf,
                                                          float* __restrict__ out) {
  const long i4 = ((long)blockIdx.x * 256 + threadIdx.x) * 4;
  ushort4 p0 = *(const ushort4*)(p + i4);
  ushort4 p1 = *(const ushort4*)(p + 4194304 + i4);
  ushort4 rr = *(const ushort4*)(ynbf + i4);
  const int nn = (int)(i4 & 1023);
  float4 bb = *(const float4*)(b2 + nn);
  float4 o;
  o.x = bf2f(p0.x) + bf2f(p1.x) + bb.x + bf2f(rr.x);
  o.y = bf2f(p0.y) + bf2f(p1.y) + bb.y + bf2f(rr.y);
  o.z = bf2f(p0.z) + bf2f(p1.z) + bb.z + bf2f(rr.z);
  o.w = bf2f(p0.w) + bf2f(p1.w) + bb.w + bf2f(rr.w);
  *(float4*)(out + i4) = o;
}

// ====== 128x128 bf16 GEMM (m97-class) =======================================
template <int EPI>
__global__ __launch_bounds__(256, 2) void gemm128_kernel(
    const u16* __restrict__ A, const u16* __restrict__ Bt,
    int K, int nk, int N,
    const float* bias0, const float* bias1, const float* bias2,
    void* out0, void* out1) {
  __shared__ __align__(16) u16 Asm[128 * 64];
  __shared__ __align__(16) u16 Bsm[128 * 64];
  const int tid = threadIdx.x;
  const int lane = tid & 63, w = tid >> 6;
  const int wm = w >> 1, wn = w & 1;
  const int q = lane & 15, g = lane >> 4;
  const long m0 = (long)blockIdx.x * 128;
  const long n0 = (long)blockIdx.y * 128;
  const int bz = blockIdx.z;
  const long koff = (long)bz * (long)nk * 64;

  f32x4 zero4 = {0.f, 0.f, 0.f, 0.f};
  f32x4 acc[4][4];
#pragma unroll
  for (int mi = 0; mi < 4; ++mi)
#pragma unroll
    for (int ni = 0; ni < 4; ++ni) acc[mi][ni] = zero4;

  for (int ks = 0; ks < nk; ++ks) {
    __syncthreads();
    const u16* ga = A + m0 * K + koff + ks * 64;
    const u16* gb = Bt + n0 * K + koff + ks * 64;
    const int base = w * 256;
#pragma unroll
    for (int i = 0; i < 4; ++i) {
      const int idx = base + i * 64 + lane;
      const int row = idx >> 3;
      const int lg = (idx & 7) ^ (row & 7);
      gl16(ga + (long)row * K + lg * 8, Asm + (long)(base + i * 64) * 8);
    }
#pragma unroll
    for (int i = 0; i < 4; ++i) {
      const int idx = base + i * 64 + lane;
      const int row = idx >> 3;
      const int lg = (idx & 7) ^ (row & 7);
      gl16(gb + (long)row * K + lg * 8, Bsm + (long)(base + i * 64) * 8);
    }
    __syncthreads();
#pragma unroll
    for (int half = 0; half < 2; ++half) {
      bf16x8 af[4], bfv[4];
#pragma unroll
      for (int mi = 0; mi < 4; ++mi) {
        const int row = wm * 64 + mi * 16 + q;
        const int ph = (half * 4 + g) ^ (row & 7);
        af[mi] = *(const bf16x8*)(Asm + row * 64 + ph * 8);
      }
#pragma unroll
      for (int ni = 0; ni < 4; ++ni) {
        const int row = wn * 64 + ni * 16 + q;
        const int ph = (half * 4 + g) ^ (row & 7);
        bfv[ni] = *(const bf16x8*)(Bsm + row * 64 + ph * 8);
      }
#pragma unroll
      for (int mi = 0; mi < 4; ++mi)
#pragma unroll
        for (int ni = 0; ni < 4; ++ni)
          acc[mi][ni] = __builtin_amdgcn_mfma_f32_16x16x32_bf16(af[mi], bfv[ni],
                                                                acc[mi][ni], 0, 0, 0);
    }
  }
#pragma unroll
  for (int mi = 0; mi < 4; ++mi) {
#pragma unroll
    for (int ni = 0; ni < 4; ++ni) {
      const long mbase = m0 + wm * 64 + mi * 16 + 4 * g;
      const long n = n0 + wn * 64 + ni * 16 + q;
      f32x4 a = acc[mi][ni];
      if constexpr (EPI == 0) {
        const int sel = (int)(n >> 10);
        const int nn = (int)(n & 1023);
        const float* bp = sel == 0 ? bias0 : (sel == 1 ? bias1 : bias2);
        const float bb2 = bp[nn];
        if (sel < 2) {
          const float sc = (sel == 0) ? 0.18033688011112043f : 1.0f;
          u16* qkp = (u16*)out0;
#pragma unroll
          for (int r = 0; r < 4; ++r)
            qkp[(mbase + r) * 2048 + n] = f2bf((a[r] + bb2) * sc);
        } else {
          const int bI = (int)(mbase >> 11);
          const int t = (int)(mbase & 2047);
          const int hh = nn >> 6, dh = nn & 63;
          ushort4 pk;
          pk.x = f2bf(a[0] + bb2); pk.y = f2bf(a[1] + bb2);
          pk.z = f2bf(a[2] + bb2); pk.w = f2bf(a[3] + bb2);
          *(ushort4*)((u16*)out1 + ((long)((bI * 16 + hh) * 64 + dh)) * 2048 + t) = pk;
        }
      } else if constexpr (EPI == 2) {
        u16* gp = (u16*)out0;
        const float bb2 = bias0[(int)n];
#pragma unroll
        for (int r = 0; r < 4; ++r) {
          const float xg = a[r] + bb2;
          const float ge = 0.5f * xg * (1.0f + erff(xg * 0.70710678118f));
          gp[(mbase + r) * N + n] = f2bf(ge);
        }
      } else {  // EPI == 5: bf16 partial per K-slice
        u16* pp = (u16*)out0 + (long)bz * 4096 * 1024;
#pragma unroll
        for (int r = 0; r < 4; ++r) pp[(mbase + r) * 1024 + n] = f2bf(a[r]);
      }
    }
  }
}

// ---------------- causal flash attention (R8 body, session-best) -------------
__device__ __forceinline__ void attn_stage(const u16* kbase, const u16* vtb, int kb,
                                           u16* Kd, u16* Vd, int tid) {
#pragma unroll
  for (int it = 0; it < 2; ++it) {
    const int gi = it * 256 + tid;
    const int row = gi >> 3;
    const int lg = (gi & 7) ^ (row & 7);
    gl16(kbase + (long)(kb * 64 + row) * 2048 + lg * 8, Kd + gi * 8);
    gl16(vtb + (long)row * 2048 + kb * 64 + lg * 8, Vd + gi * 8);
  }
}

__device__ __forceinline__ void softmax_slab(const f32x4 st[4], bool diag, int qrow,
                                             int kb, int g, int q15,
                                             float& m2, float& l, u16* prow,
                                             float al[4]) {
  float sv[4][4];
  float rmax = -1e30f;
#pragma unroll
  for (int sub = 0; sub < 4; ++sub)
#pragma unroll
    for (int r = 0; r < 4; ++r) {
      float s_ = st[sub][r];
      if (diag) {
        const int key = kb * 64 + sub * 16 + 4 * g + r;
        s_ = (key > qrow) ? -1e30f : s_;
      }
      sv[sub][r] = s_;
      rmax = fmaxf(rmax, s_);
    }
  rmax = fmaxf(rmax, __shfl_xor(rmax, 16));
  rmax = fmaxf(rmax, __shfl_xor(rmax, 32));
  const float mnew = fmaxf(m2, rmax);
  const float alpha = exp2a(m2 - mnew);
  float psum = 0.f;
#pragma unroll
  for (int sub = 0; sub < 4; ++sub) {
    const float p0 = exp2a(sv[sub][0] - mnew);
    const float p1 = exp2a(sv[sub][1] - mnew);
    const float p2 = exp2a(sv[sub][2] - mnew);
    const float p3 = exp2a(sv[sub][3] - mnew);
    uint2 u;
    u.x = pk2(p0, p1);
    u.y = pk2(p2, p3);
    *(uint2*)(prow + sub * 16 + 4 * g) = u;
    psum += (p0 + p1) + (p2 + p3);
  }
  psum += __shfl_xor(psum, 16);
  psum += __shfl_xor(psum, 32);
  l = l * alpha + psum;
  m2 = mnew;
#pragma unroll
  for (int r = 0; r < 4; ++r) al[r] = __shfl(alpha, 4 * g + r);
}

__global__ __launch_bounds__(256, 2) void attn_kernel(const u16* __restrict__ qk,
                                                      const u16* __restrict__ vT,
                                                      u16* __restrict__ o) {
  __shared__ __align__(16) u16 Ksm[2][64 * 64];
  __shared__ __align__(16) u16 Vsm[2][64 * 64];
  __shared__ __align__(16) u16 Psm[8][16][72];
  const int lid = blockIdx.x;
  const int xcd = lid & 7, s6 = lid >> 3;
  const int b2 = (s6 >> 4) & 3, xr = s6 & 15;
  const int qs = (b2 & 2) ? (15 - xr) : xr;
  const int bh = xcd + 8 * b2;
  const int b = bh >> 4, h = bh & 15;
  const int tid = threadIdx.x, lane = tid & 63, w = tid >> 6;
  const int q15 = lane & 15, g = lane >> 4;
  const u16* qbase = qk + (long)b * 2048 * 2048 + h * 64;
  const u16* kbase = qbase + 1024;
  const u16* vtb = vT + (long)bh * 64 * 2048;
  f32x4 zero4 = {0.f, 0.f, 0.f, 0.f};

  const int r0 = qs * 128 + w * 16 + q15;
  bf16x8 qa[2][2];
  qa[0][0] = *(const bf16x8*)(qbase + (long)r0 * 2048 + g * 8);
  qa[0][1] = *(const bf16x8*)(qbase + (long)r0 * 2048 + 32 + g * 8);
  qa[1][0] = *(const bf16x8*)(qbase + (long)(r0 + 64) * 2048 + g * 8);
  qa[1][1] = *(const bf16x8*)(qbase + (long)(r0 + 64) * 2048 + 32 + g * 8);

  f32x4 oa0[4], oa1[4];
#pragma unroll
  for (int dv = 0; dv < 4; ++dv) { oa0[dv] = zero4; oa1[dv] = zero4; }
  float m20 = -1e30f, l0 = 0.f, m21 = -1e30f, l1 = 0.f;
  const int kbmax = 2 * qs + 1;

  attn_stage(kbase, vtb, 0, Ksm[0], Vsm[0], tid);
  VMC0();
  __syncthreads();

  for (int kb = 0; kb <= kbmax; ++kb) {
    const int buf = kb & 1;
    if (kb < kbmax) attn_stage(kbase, vtb, kb + 1, Ksm[buf ^ 1], Vsm[buf ^ 1], tid);
    const u16* Kb = Ksm[buf];
    const u16* Vb = Vsm[buf];
    const bool s0on = (kb <= 2 * qs);
    f32x4 st0[4], st1[4];
#pragma unroll
    for (int sub = 0; sub < 4; ++sub) {
      const int row = sub * 16 + q15;
      const bf16x8 ka0 = *(const bf16x8*)(Kb + row * 64 + ((g ^ (row & 7)) * 8));
      const bf16x8 ka1 = *(const bf16x8*)(Kb + row * 64 + (((4 + g) ^ (row & 7)) * 8));
      f32x4 z = zero4;
      z = __builtin_amdgcn_mfma_f32_16x16x32_bf16(ka0, qa[1][0], z, 0, 0, 0);
      z = __builtin_amdgcn_mfma_f32_16x16x32_bf16(ka1, qa[1][1], z, 0, 0, 0);
      st1[sub] = z;
      if (s0on) {
        f32x4 z0 = zero4;
        z0 = __builtin_amdgcn_mfma_f32_16x16x32_bf16(ka0, qa[0][0], z0, 0, 0, 0);
        z0 = __builtin_amdgcn_mfma_f32_16x16x32_bf16(ka1, qa[0][1], z0, 0, 0, 0);
        st0[sub] = z0;
      }
    }
    float al0[4], al1[4];
    if (s0on)
      softmax_slab(st0, kb == 2 * qs, r0, kb, g, q15, m20, l0, &Psm[w * 2][q15][0], al0);
    softmax_slab(st1, kb == 2 * qs + 1, r0 + 64, kb, g, q15, m21, l1,
                 &Psm[w * 2 + 1][q15][0], al1);
    if (s0on)
#pragma unroll
      for (int dv = 0; dv < 4; ++dv) {
        oa0[dv][0] *= al0[0]; oa0[dv][1] *= al0[1];
        oa0[dv][2] *= al0[2]; oa0[dv][3] *= al0[3];
      }
#pragma unroll
    for (int dv = 0; dv < 4; ++dv) {
      oa1[dv][0] *= al1[0]; oa1[dv][1] *= al1[1];
      oa1[dv][2] *= al1[2]; oa1[dv][3] *= al1[3];
    }
    LGKM0();
#pragma unroll
    for (int half = 0; half < 2; ++half) {
      const bf16x8 pa0 = *(const bf16x8*)(&Psm[w * 2][q15][half * 32 + 8 * g]);
      const bf16x8 pa1 = *(const bf16x8*)(&Psm[w * 2 + 1][q15][half * 32 + 8 * g]);
#pragma unroll
      for (int dv = 0; dv < 4; ++dv) {
        const int row = dv * 16 + q15;
        const bf16x8 vb = *(const bf16x8*)(Vb + row * 64 + (((half * 4 + g) ^ (row & 7)) * 8));
        if (s0on) oa0[dv] = __builtin_amdgcn_mfma_f32_16x16x32_bf16(pa0, vb, oa0[dv], 0, 0, 0);
        oa1[dv] = __builtin_amdgcn_mfma_f32_16x16x32_bf16(pa1, vb, oa1[dv], 0, 0, 0);
      }
    }
    VMC0();
    __syncthreads();
  }
  const float li0 = 1.0f / l0, li1 = 1.0f / l1;
  float v0[4], v1[4];
#pragma unroll
  for (int r = 0; r < 4; ++r) {
    v0[r] = __shfl(li0, 4 * g + r);
    v1[r] = __shfl(li1, 4 * g + r);
  }
  const int tok0 = b * 2048 + qs * 128 + w * 16;
#pragma unroll
  for (int dv = 0; dv < 4; ++dv)
#pragma unroll
    for (int r = 0; r < 4; ++r) {
      o[(long)(tok0 + 4 * g + r) * 1024 + h * 64 + dv * 16 + q15] =
          f2bf(oa0[dv][r] * v0[r]);
      o[(long)(tok0 + 64 + 4 * g + r) * 1024 + h * 64 + dv * 16 + q15] =
          f2bf(oa1[dv][r] * v1[r]);
    }
}

extern "C" void kernel_launch(void* const* d_in, const int* in_sizes, int n_in,
                              void* d_out, int out_size, void* d_ws, size_t ws_size,
                              hipStream_t stream) {
  (void)in_sizes; (void)n_in; (void)out_size; (void)ws_size;
  const float* x  = (const float*)d_in[0];
  const float* Wq = (const float*)d_in[1];
  const float* bq = (const float*)d_in[2];
  const float* Wk = (const float*)d_in[3];
  const float* bk = (const float*)d_in[4];
  const float* Wv = (const float*)d_in[5];
  const float* bv = (const float*)d_in[6];
  const float* Wo = (const float*)d_in[7];
  const float* bo = (const float*)d_in[8];
  const float* g1 = (const float*)d_in[9];
  const float* be1 = (const float*)d_in[10];
  const float* g2 = (const float*)d_in[11];
  const float* be2 = (const float*)d_in[12];
  const float* W1 = (const float*)d_in[13];
  const float* b1 = (const float*)d_in[14];
  const float* W2 = (const float*)d_in[15];
  const float* b2 = (const float*)d_in[16];

  char* ws = (char*)d_ws;
  u16*   xn_bf = (u16*)  (ws + 0);          // LN1 out bf16 (GEMM A + residual)
  u16*   WqkvT = (u16*)  (ws + 25165824);
  u16*   WoT   = (u16*)  (ws + 31457280);
  u16*   W1T   = (u16*)  (ws + 33554432);
  u16*   W2T   = (u16*)  (ws + 41943040);
  u16*   qkb   = (u16*)  (ws + 50331648);
  u16*   vTb   = (u16*)  (ws + 67108864);
  u16*   ah    = (u16*)  (ws + 75497472);
  u16*   pwo0  = (u16*)  (ws + 50331648);   // Wo partials (qkb dead after attn)
  u16*   gbuf  = (u16*)  (ws + 50331648);   // FFN hidden 32MB (dead region)
  u16*   part  = (u16*)  (ws + 8388608);    // FFN2 partials 2x8MB
  u16*   yn_bf = (u16*)  (ws + 83886080);   // LN2 out bf16 (GEMM A + residual)

  dim3 tb(32, 8), b256(256);
  wprep_kernel<<<dim3(16384), tb, 0, stream>>>(Wq, Wk, Wv, Wo, W1, W2,
                                               WqkvT, WoT, W1T, W2T,
                                               x, g1, be1, xn_bf);
  gemm128_kernel<0><<<dim3(32, 24, 1), b256, 0, stream>>>(xn_bf, WqkvT, 1024, 16, 3072,
                                                          bq, bk, bv, qkb, vTb);
  attn_kernel<<<dim3(512), b256, 0, stream>>>(qkb, vTb, ah);
  gemm128_kernel<5><<<dim3(32, 8, 2), b256, 0, stream>>>(ah, WoT, 1024, 8, 1024,
                                                         nullptr, nullptr, nullptr, pwo0, nullptr);
  ln2_fused_kernel<<<dim3(4096), b256, 0, stream>>>(pwo0, pwo0 + 4194304, bo, xn_bf,
                                                    g2, be2, yn_bf);
  gemm128_kernel<2><<<dim3(32, 32, 1), b256, 0, stream>>>(yn_bf, W1T, 1024, 16, 4096,
                                                          b1, nullptr, nullptr, gbuf, nullptr);
  gemm128_kernel<5><<<dim3(32, 8, 2), b256, 0, stream>>>(gbuf, W2T, 4096, 32, 1024,
                                                         nullptr, nullptr, nullptr, part, nullptr);
  ffn2_reduce_kernel<<<dim3(4096), b256, 0, stream>>>(part, b2, yn_bf, (float*)d_out);
}